// Round 1
// baseline (400.365 us; speedup 1.0000x reference)
//
#include <hip/hip_runtime.h>
#include <hip/hip_bf16.h>

// ===== Problem constants =====
// B=8, N=1025, C=768, H=12, HD=64
constexpr int NTOK   = 1025;
constexpr int M      = 8 * NTOK;      // 8200 tokens
constexpr int MP     = 8320;          // 65 * 128 padded rows
constexpr int KDIM   = 768;
constexpr int NQKV   = 2304;
constexpr int NKVPAD = 1088;          // 17*64 padded kv length for vT
constexpr float SCALE = 0.125f;       // 64^-0.5

using bf16x8 = __attribute__((ext_vector_type(8))) short;
using f32x4  = __attribute__((ext_vector_type(4))) float;

__device__ __forceinline__ f32x4 mfma_bf16(bf16x8 a, bf16x8 b, f32x4 c) {
  return __builtin_amdgcn_mfma_f32_16x16x32_bf16(a, b, c, 0, 0, 0);
}

__device__ __forceinline__ void gl16(const void* g, void* l) {
  __builtin_amdgcn_global_load_lds(
      (const __attribute__((address_space(1))) void*)g,
      (__attribute__((address_space(3))) void*)l, 16, 0, 0);
}

// ===== Workspace layout (bytes), all 256-aligned =====
constexpr size_t OFF_XHI  = 0;                          // MP*768 bf16
constexpr size_t SZ_X     = (size_t)MP * KDIM * 2;      // 12,779,520
constexpr size_t OFF_XLO  = OFF_XHI + SZ_X;
constexpr size_t OFF_WQHI = OFF_XLO + SZ_X;
constexpr size_t SZ_WQ    = (size_t)NQKV * KDIM * 2;    // 3,538,944
constexpr size_t OFF_WQLO = OFF_WQHI + SZ_WQ;
constexpr size_t OFF_PWHI = OFF_WQLO + SZ_WQ;
constexpr size_t SZ_PW    = (size_t)KDIM * KDIM * 2;    // 1,179,648
constexpr size_t OFF_PWLO = OFF_PWHI + SZ_PW;
constexpr size_t OFF_Q    = OFF_PWLO + SZ_PW;
constexpr size_t SZ_QK    = (size_t)96 * NTOK * 64 * 2; // 12,595,200
constexpr size_t OFF_K    = OFF_Q + SZ_QK;
constexpr size_t OFF_VT   = OFF_K + SZ_QK;
constexpr size_t SZ_VT    = (size_t)96 * 64 * NKVPAD * 2; // 13,369,344
constexpr size_t OFF_AOHI = OFF_VT + SZ_VT;
constexpr size_t OFF_AOLO = OFF_AOHI + SZ_X;
// total ~99.1 MB

// ===== K0: fp32 -> (hi,lo) bf16 split, zero tail =====
__global__ void k_split(const float* __restrict__ src, __hip_bfloat16* __restrict__ hi,
                        __hip_bfloat16* __restrict__ lo, int n_src, int n_dst) {
  int i = blockIdx.x * 256 + threadIdx.x;
  if (i >= n_dst) return;
  float v = (i < n_src) ? src[i] : 0.0f;
  __hip_bfloat16 h = __float2bfloat16(v);
  hi[i] = h;
  lo[i] = __float2bfloat16(v - __bfloat162float(h));
}

// zero vT pad columns (keys 1025..1087) so PV MFMA never sees NaN garbage
__global__ void k_zero_vt(__hip_bfloat16* __restrict__ vt) {
  int i = blockIdx.x * 256 + threadIdx.x;
  constexpr int NPADC = NKVPAD - NTOK; // 63
  if (i >= 96 * 64 * NPADC) return;
  int r = i / NPADC;
  int c = NTOK + (i - r * NPADC);
  vt[(size_t)r * NKVPAD + c] = __float2bfloat16(0.0f);
}

// ===== GEMM core (128x128 tile, BK=32, split hi/lo 3-term), two epilogues =====
// EPI=0: QKV -> bias + RoPE -> q,k ([bh][t][d] bf16) and vT ([bh][d][t_pad] bf16)
// EPI=1: proj -> bias -> fp32 d_out
template <int EPI>
__global__ __launch_bounds__(256) void k_gemm(
    const __hip_bfloat16* __restrict__ Ahi, const __hip_bfloat16* __restrict__ Alo,
    const __hip_bfloat16* __restrict__ Bhi, const __hip_bfloat16* __restrict__ Blo,
    const float* __restrict__ bias, const float* __restrict__ sinp,
    const float* __restrict__ cosp, __hip_bfloat16* __restrict__ o_q,
    __hip_bfloat16* __restrict__ o_k, __hip_bfloat16* __restrict__ o_vt,
    float* __restrict__ o_f32) {
  const int tid = threadIdx.x;
  const int w = tid >> 6, lane = tid & 63;
  const int wm = w >> 1, wn = w & 1;
  const int l15 = lane & 15, q4 = lane >> 4;
  const int mBase = blockIdx.y * 128, nBase = blockIdx.x * 128;

  __shared__ __hip_bfloat16 sm[4 * 4096]; // Ahi,Alo,Bhi,Blo tiles [128][32]
  __hip_bfloat16* sAh = sm;
  __hip_bfloat16* sAl = sm + 4096;
  __hip_bfloat16* sBh = sm + 8192;
  __hip_bfloat16* sBl = sm + 12288;

  const char* pAh = (const char*)Ahi + (size_t)mBase * (KDIM * 2);
  const char* pAl = (const char*)Alo + (size_t)mBase * (KDIM * 2);
  const char* pBh = (const char*)Bhi + (size_t)nBase * (KDIM * 2);
  const char* pBl = (const char*)Blo + (size_t)nBase * (KDIM * 2);

  f32x4 acc[4][4] = {};

  for (int kt = 0; kt < KDIM / 32; ++kt) {
    const int kofs = kt * 64; // bytes into each row
#pragma unroll
    for (int i = 0; i < 2; ++i) {
      const int o = i * 256 + tid; // 16B chunk index, 512 chunks per tile
      const size_t rb = (size_t)(o >> 2) * (KDIM * 2) + ((o & 3) << 4) + kofs;
      gl16(pAh + rb, (char*)sAh + (size_t)o * 16);
      gl16(pAl + rb, (char*)sAl + (size_t)o * 16);
      gl16(pBh + rb, (char*)sBh + (size_t)o * 16);
      gl16(pBl + rb, (char*)sBl + (size_t)o * 16);
    }
    __syncthreads();
    bf16x8 fAh[4], fAl[4], fBh[4], fBl[4];
#pragma unroll
    for (int mt = 0; mt < 4; ++mt) {
      const int r = wm * 64 + mt * 16 + l15;
      fAh[mt] = *(const bf16x8*)((const char*)sAh + r * 64 + q4 * 16);
      fAl[mt] = *(const bf16x8*)((const char*)sAl + r * 64 + q4 * 16);
    }
#pragma unroll
    for (int nt = 0; nt < 4; ++nt) {
      const int r = wn * 64 + nt * 16 + l15;
      fBh[nt] = *(const bf16x8*)((const char*)sBh + r * 64 + q4 * 16);
      fBl[nt] = *(const bf16x8*)((const char*)sBl + r * 64 + q4 * 16);
    }
#pragma unroll
    for (int mt = 0; mt < 4; ++mt)
#pragma unroll
      for (int nt = 0; nt < 4; ++nt) {
        acc[mt][nt] = mfma_bf16(fAh[mt], fBh[nt], acc[mt][nt]);
        acc[mt][nt] = mfma_bf16(fAh[mt], fBl[nt], acc[mt][nt]);
        acc[mt][nt] = mfma_bf16(fAl[mt], fBh[nt], acc[mt][nt]);
      }
    __syncthreads();
  }

  // epilogue; C layout: col = lane&15, row = 4*(lane>>4)+j
#pragma unroll
  for (int mt = 0; mt < 4; ++mt)
#pragma unroll
    for (int j = 0; j < 4; ++j) {
      const int gm = mBase + wm * 64 + mt * 16 + q4 * 4 + j;
      if (gm >= M) continue;
      if (EPI == 0) {
        const int b = gm / NTOK;
        const int t = gm - b * NTOK;
#pragma unroll
        for (int nt = 0; nt < 4; ++nt) {
          const int gc = nBase + wn * 64 + nt * 16 + l15;
          float v = acc[mt][nt][j] + bias[gc];
          const int three = gc / 768;
          const int hd = gc - three * 768;
          const int h = hd >> 6, d = hd & 63;
          const int bh = b * 12 + h;
          if (three == 2) {
            o_vt[((size_t)bh * 64 + d) * NKVPAD + t] = __float2bfloat16(v);
          } else {
            if (t > 0) {
              const float pv = acc[mt][nt ^ 2][j] + bias[gc ^ 32];
              const int so = (t - 1) * 64 + d;
              v = v * cosp[so] + ((d < 32) ? -pv : pv) * sinp[so];
            }
            const __hip_bfloat16 bv = __float2bfloat16(v);
            if (three == 0)
              o_q[((size_t)bh * NTOK + t) * 64 + d] = bv;
            else
              o_k[((size_t)bh * NTOK + t) * 64 + d] = bv;
          }
        }
      } else {
#pragma unroll
        for (int nt = 0; nt < 4; ++nt) {
          const int gc = nBase + wn * 64 + nt * 16 + l15;
          o_f32[(size_t)gm * 768 + gc] = acc[mt][nt][j] + bias[gc];
        }
      }
    }
}

// ===== K2: flash attention, 4 waves x 32 q-rows, KV tiles of 64 =====
__global__ __launch_bounds__(256) void k_attn(
    const __hip_bfloat16* __restrict__ Q, const __hip_bfloat16* __restrict__ Kk,
    const __hip_bfloat16* __restrict__ VT, __hip_bfloat16* __restrict__ aohi,
    __hip_bfloat16* __restrict__ aolo) {
  __shared__ __hip_bfloat16 Pl[4][32][72]; // per-wave P tile, padded rows
  const int tid = threadIdx.x, w = tid >> 6, lane = tid & 63;
  const int l15 = lane & 15, q4 = lane >> 4;
  const int bh = blockIdx.y;
  const int qb = blockIdx.x * 128 + w * 32;
  const size_t qbase = (size_t)bh * NTOK * 64;

  // Q fragments (rows clamped; pad rows are discarded at store)
  bf16x8 qa[2][2];
#pragma unroll
  for (int mt = 0; mt < 2; ++mt) {
    int t = qb + mt * 16 + l15;
    if (t > NTOK - 1) t = NTOK - 1;
#pragma unroll
    for (int ks = 0; ks < 2; ++ks)
      qa[mt][ks] = *(const bf16x8*)(Q + qbase + (size_t)t * 64 + ks * 32 + q4 * 8);
  }

  f32x4 accO[2][4] = {};
  float mrun[2][4], lrun[2][4];
#pragma unroll
  for (int mt = 0; mt < 2; ++mt)
#pragma unroll
    for (int j = 0; j < 4; ++j) {
      mrun[mt][j] = -1e30f;
      lrun[mt][j] = 0.0f;
    }

  for (int kt = 0; kt < 17; ++kt) {
    const int kb0 = kt * 64;
    // S = Q K^T
    f32x4 s[2][4] = {};
    {
      bf16x8 kfr[2][4];
#pragma unroll
      for (int nt = 0; nt < 4; ++nt) {
        int krow = kb0 + nt * 16 + l15;
        if (krow > NTOK - 1) krow = NTOK - 1;
#pragma unroll
        for (int ks = 0; ks < 2; ++ks)
          kfr[ks][nt] =
              *(const bf16x8*)(Kk + qbase + (size_t)krow * 64 + ks * 32 + q4 * 8);
      }
#pragma unroll
      for (int mt = 0; mt < 2; ++mt)
#pragma unroll
        for (int nt = 0; nt < 4; ++nt)
#pragma unroll
          for (int ks = 0; ks < 2; ++ks)
            s[mt][nt] = mfma_bf16(qa[mt][ks], kfr[ks][nt], s[mt][nt]);
    }
    // online softmax (rows live in 16-lane groups; reduce via shfl_xor 1..8)
#pragma unroll
    for (int mt = 0; mt < 2; ++mt)
#pragma unroll
      for (int j = 0; j < 4; ++j) {
        float sv[4];
        float mx = -1e30f;
#pragma unroll
        for (int nt = 0; nt < 4; ++nt) {
          float v = s[mt][nt][j] * SCALE;
          if (kb0 + nt * 16 + l15 > NTOK - 1) v = -1e30f;
          sv[nt] = v;
          mx = fmaxf(mx, v);
        }
#pragma unroll
        for (int off = 1; off < 16; off <<= 1) mx = fmaxf(mx, __shfl_xor(mx, off));
        const float mold = mrun[mt][j];
        const float mnew = fmaxf(mold, mx);
        const float fsc = __expf(mold - mnew);
        float sum = 0.0f;
        __hip_bfloat16 pb[4];
#pragma unroll
        for (int nt = 0; nt < 4; ++nt) {
          float p = __expf(sv[nt] - mnew);
          sum += p;
          pb[nt] = __float2bfloat16(p);
        }
#pragma unroll
        for (int off = 1; off < 16; off <<= 1) sum += __shfl_xor(sum, off);
        mrun[mt][j] = mnew;
        lrun[mt][j] = lrun[mt][j] * fsc + sum;
#pragma unroll
        for (int nd = 0; nd < 4; ++nd) accO[mt][nd][j] *= fsc;
        const int row = mt * 16 + q4 * 4 + j;
#pragma unroll
        for (int nt = 0; nt < 4; ++nt) Pl[w][row][nt * 16 + l15] = pb[nt];
      }
    // PV (wave-private LDS; compiler orders ds_write->ds_read via lgkmcnt)
    bf16x8 pa[2][2], vf[2][4];
#pragma unroll
    for (int mt = 0; mt < 2; ++mt)
#pragma unroll
      for (int ks = 0; ks < 2; ++ks)
        pa[mt][ks] = *(const bf16x8*)&Pl[w][mt * 16 + l15][ks * 32 + q4 * 8];
#pragma unroll
    for (int nd = 0; nd < 4; ++nd)
#pragma unroll
      for (int ks = 0; ks < 2; ++ks)
        vf[ks][nd] = *(const bf16x8*)(VT + ((size_t)bh * 64 + nd * 16 + l15) * NKVPAD +
                                      kb0 + ks * 32 + q4 * 8);
#pragma unroll
    for (int mt = 0; mt < 2; ++mt)
#pragma unroll
      for (int nd = 0; nd < 4; ++nd)
#pragma unroll
        for (int ks = 0; ks < 2; ++ks)
          accO[mt][nd] = mfma_bf16(pa[mt][ks], vf[ks][nd], accO[mt][nd]);
  }

  // store attn_out as hi/lo split at [b*1025+t][h*64+d]
  const int b = bh / 12, h = bh - (bh / 12) * 12;
#pragma unroll
  for (int mt = 0; mt < 2; ++mt)
#pragma unroll
    for (int j = 0; j < 4; ++j) {
      const int t = qb + mt * 16 + q4 * 4 + j;
      if (t > NTOK - 1) continue;
      const float inv = 1.0f / lrun[mt][j];
      const size_t ro = ((size_t)(b * NTOK + t)) * 768 + h * 64;
#pragma unroll
      for (int nd = 0; nd < 4; ++nd) {
        const int d = nd * 16 + l15;
        const float o = accO[mt][nd][j] * inv;
        const __hip_bfloat16 oh = __float2bfloat16(o);
        aohi[ro + d] = oh;
        aolo[ro + d] = __float2bfloat16(o - __bfloat162float(oh));
      }
    }
}

extern "C" void kernel_launch(void* const* d_in, const int* in_sizes, int n_in,
                              void* d_out, int out_size, void* d_ws, size_t ws_size,
                              hipStream_t stream) {
  const float* x = (const float*)d_in[0];
  const float* sinp = (const float*)d_in[1];
  const float* cosp = (const float*)d_in[2];
  const float* qkvw = (const float*)d_in[3];
  const float* qkvb = (const float*)d_in[4];
  const float* projw = (const float*)d_in[5];
  const float* projb = (const float*)d_in[6];

  char* ws = (char*)d_ws;
  __hip_bfloat16* xhi = (__hip_bfloat16*)(ws + OFF_XHI);
  __hip_bfloat16* xlo = (__hip_bfloat16*)(ws + OFF_XLO);
  __hip_bfloat16* wqhi = (__hip_bfloat16*)(ws + OFF_WQHI);
  __hip_bfloat16* wqlo = (__hip_bfloat16*)(ws + OFF_WQLO);
  __hip_bfloat16* pwhi = (__hip_bfloat16*)(ws + OFF_PWHI);
  __hip_bfloat16* pwlo = (__hip_bfloat16*)(ws + OFF_PWLO);
  __hip_bfloat16* qb = (__hip_bfloat16*)(ws + OFF_Q);
  __hip_bfloat16* kb = (__hip_bfloat16*)(ws + OFF_K);
  __hip_bfloat16* vt = (__hip_bfloat16*)(ws + OFF_VT);
  __hip_bfloat16* aohi = (__hip_bfloat16*)(ws + OFF_AOHI);
  __hip_bfloat16* aolo = (__hip_bfloat16*)(ws + OFF_AOLO);

  // K0: splits (x gets zero tail to MP rows)
  {
    int n_src = M * KDIM, n_dst = MP * KDIM;
    k_split<<<(n_dst + 255) / 256, 256, 0, stream>>>(x, xhi, xlo, n_src, n_dst);
    int nw = NQKV * KDIM;
    k_split<<<(nw + 255) / 256, 256, 0, stream>>>(qkvw, wqhi, wqlo, nw, nw);
    int np = KDIM * KDIM;
    k_split<<<(np + 255) / 256, 256, 0, stream>>>(projw, pwhi, pwlo, np, np);
    int nz = 96 * 64 * (NKVPAD - NTOK);
    k_zero_vt<<<(nz + 255) / 256, 256, 0, stream>>>(vt);
  }
  // K1: QKV GEMM + bias + RoPE -> q, k, vT
  k_gemm<0><<<dim3(NQKV / 128, MP / 128), 256, 0, stream>>>(
      xhi, xlo, wqhi, wqlo, qkvb, sinp, cosp, qb, kb, vt, nullptr);
  // K2: flash attention -> attn_out hi/lo
  k_attn<<<dim3(9, 96), 256, 0, stream>>>(qb, kb, vt, aohi, aolo);
  // K3: proj GEMM + bias -> fp32 out
  k_gemm<1><<<dim3(KDIM / 128, MP / 128), 256, 0, stream>>>(
      aohi, aolo, pwhi, pwlo, projb, nullptr, nullptr, nullptr, nullptr, nullptr,
      (float*)d_out);
}

// Round 2
// 356.351 us; speedup vs baseline: 1.1235x; 1.1235x over previous
//
#include <hip/hip_runtime.h>
#include <hip/hip_bf16.h>

// ===== Problem constants =====
// B=8, N=1025, C=768, H=12, HD=64
constexpr int NTOK   = 1025;
constexpr int M      = 8 * NTOK;      // 8200 tokens
constexpr int MP     = 8320;          // 65 * 128 padded rows
constexpr int KDIM   = 768;
constexpr int NQKV   = 2304;
constexpr int NKVPAD = 1088;          // 17*64 padded kv length for vT
constexpr float SCALE = 0.125f;       // 64^-0.5

using bf16x8 = __attribute__((ext_vector_type(8))) short;
using f32x4  = __attribute__((ext_vector_type(4))) float;

__device__ __forceinline__ f32x4 mfma_bf16(bf16x8 a, bf16x8 b, f32x4 c) {
  return __builtin_amdgcn_mfma_f32_16x16x32_bf16(a, b, c, 0, 0, 0);
}

__device__ __forceinline__ void gl16(const void* g, void* l) {
  __builtin_amdgcn_global_load_lds(
      (const __attribute__((address_space(1))) void*)g,
      (__attribute__((address_space(3))) void*)l, 16, 0, 0);
}

// ===== Workspace layout (bytes), all 256-aligned =====
constexpr size_t SZ_X     = (size_t)MP * KDIM * 2;        // 12,779,520
constexpr size_t SZ_WQ    = (size_t)NQKV * KDIM * 2;      // 3,538,944
constexpr size_t SZ_PW    = (size_t)KDIM * KDIM * 2;      // 1,179,648
constexpr size_t SZ_QK    = (size_t)96 * NTOK * 64 * 2;   // 12,595,200
constexpr size_t SZ_VT    = (size_t)96 * 64 * NKVPAD * 2; // 13,369,344
constexpr size_t OFF_XHI  = 0;
constexpr size_t OFF_XLO  = OFF_XHI + SZ_X;
constexpr size_t OFF_WQHI = OFF_XLO + SZ_X;
constexpr size_t OFF_PWHI = OFF_WQHI + SZ_WQ;
constexpr size_t OFF_PWLO = OFF_PWHI + SZ_PW;
constexpr size_t OFF_Q    = OFF_PWLO + SZ_PW;
constexpr size_t OFF_K    = OFF_Q + SZ_QK;
constexpr size_t OFF_VT   = OFF_K + SZ_QK;
constexpr size_t OFF_AO   = OFF_VT + SZ_VT;
// total ~83 MB

// ===== K0a: fp32 -> (hi,lo) bf16 split, zero tail =====
__global__ void k_split(const float* __restrict__ src, __hip_bfloat16* __restrict__ hi,
                        __hip_bfloat16* __restrict__ lo, int n_src, int n_dst) {
  int i = blockIdx.x * 256 + threadIdx.x;
  if (i >= n_dst) return;
  float v = (i < n_src) ? src[i] : 0.0f;
  __hip_bfloat16 h = __float2bfloat16(v);
  hi[i] = h;
  lo[i] = __float2bfloat16(v - __bfloat162float(h));
}

// K0b: fp32 -> bf16 (hi only)
__global__ void k_tobf16(const float* __restrict__ src, __hip_bfloat16* __restrict__ dst,
                         int n) {
  int i = blockIdx.x * 256 + threadIdx.x;
  if (i >= n) return;
  dst[i] = __float2bfloat16(src[i]);
}

// zero vT pad columns (keys 1025..1087) so PV MFMA never sees NaN garbage
__global__ void k_zero_vt(__hip_bfloat16* __restrict__ vt) {
  int i = blockIdx.x * 256 + threadIdx.x;
  constexpr int NPADC = NKVPAD - NTOK; // 63
  if (i >= 96 * 64 * NPADC) return;
  int r = i / NPADC;
  int c = NTOK + (i - r * NPADC);
  vt[(size_t)r * NKVPAD + c] = __float2bfloat16(0.0f);
}

// ===== GEMM core: 128x128 tile, BK=32, 2-term split, swizzled LDS =====
// SPLIT_A=1: acc = Ah*Bh + Al*Bh   (Asec = A_lo, row base mBase)
// SPLIT_A=0: acc = Ah*Bh + Ah*Bl   (Asec = B_lo, row base nBase)
// LDS swizzle (conflict-free ds_read_b128 with linear global_load_lds dest):
//   chunk c (16B) holds global (row=c>>2, slot=(c&3)^((row>>1)&3)) of the tile;
//   4-lane groups still fetch the same contiguous 64B from global (coalesced).
// EPI=0: QKV -> bias + RoPE -> q,k ([bh][t][d] bf16) and vT ([bh][d][t_pad] bf16)
// EPI=1: proj -> bias -> fp32 d_out
template <int EPI, bool SPLIT_A>
__global__ __launch_bounds__(256) void k_gemm(
    const __hip_bfloat16* __restrict__ Ahi, const __hip_bfloat16* __restrict__ Asec,
    const __hip_bfloat16* __restrict__ Bhi, const float* __restrict__ bias,
    const float* __restrict__ sinp, const float* __restrict__ cosp,
    __hip_bfloat16* __restrict__ o_q, __hip_bfloat16* __restrict__ o_k,
    __hip_bfloat16* __restrict__ o_vt, float* __restrict__ o_f32) {
  const int tid = threadIdx.x;
  const int w = tid >> 6, lane = tid & 63;
  const int wm = w >> 1, wn = w & 1;
  const int l15 = lane & 15, q4 = lane >> 4;
  const int mBase = blockIdx.y * 128, nBase = blockIdx.x * 128;

  __shared__ __hip_bfloat16 sm[3 * 4096]; // three [128][32] bf16 tiles
  char* s0 = (char*)sm;          // A_hi
  char* s1 = s0 + 8192;          // SPLIT_A ? A_lo : B_lo
  char* s2 = s0 + 16384;         // B_hi

  const char* p0 = (const char*)Ahi + (size_t)mBase * (KDIM * 2);
  const char* p1 = (const char*)Asec + (size_t)(SPLIT_A ? mBase : nBase) * (KDIM * 2);
  const char* p2 = (const char*)Bhi + (size_t)nBase * (KDIM * 2);

  const int slog = ((tid & 3) ^ ((tid >> 3) & 3)) << 4; // staged slot byte offset
  const int ph = ((q4 ^ ((l15 >> 1) & 3)) << 4);        // fragment slot byte offset

  f32x4 acc[4][4] = {};

  for (int kt = 0; kt < KDIM / 32; ++kt) {
    const int kofs = kt * 64; // bytes into each row
#pragma unroll
    for (int i = 0; i < 2; ++i) {
      const int c = i * 256 + tid; // 16B chunk index, 512 per tile
      const size_t rb = (size_t)(i * 64 + (tid >> 2)) * (KDIM * 2) + slog + kofs;
      gl16(p0 + rb, s0 + (size_t)c * 16);
      gl16(p1 + rb, s1 + (size_t)c * 16);
      gl16(p2 + rb, s2 + (size_t)c * 16);
    }
    __syncthreads();
    bf16x8 a0[4], a1[4], b0[4], b1[4];
#pragma unroll
    for (int mt = 0; mt < 4; ++mt) {
      const int r = wm * 64 + mt * 16 + l15;
      a0[mt] = *(const bf16x8*)(s0 + r * 64 + ph);
      if (SPLIT_A) a1[mt] = *(const bf16x8*)(s1 + r * 64 + ph);
    }
#pragma unroll
    for (int nt = 0; nt < 4; ++nt) {
      const int r = wn * 64 + nt * 16 + l15;
      b0[nt] = *(const bf16x8*)(s2 + r * 64 + ph);
      if (!SPLIT_A) b1[nt] = *(const bf16x8*)(s1 + r * 64 + ph);
    }
#pragma unroll
    for (int mt = 0; mt < 4; ++mt)
#pragma unroll
      for (int nt = 0; nt < 4; ++nt) {
        acc[mt][nt] = mfma_bf16(a0[mt], b0[nt], acc[mt][nt]);
        if (SPLIT_A)
          acc[mt][nt] = mfma_bf16(a1[mt], b0[nt], acc[mt][nt]);
        else
          acc[mt][nt] = mfma_bf16(a0[mt], b1[nt], acc[mt][nt]);
      }
    __syncthreads();
  }

  // epilogue; C layout: col = lane&15, row = 4*(lane>>4)+j
#pragma unroll
  for (int mt = 0; mt < 4; ++mt)
#pragma unroll
    for (int j = 0; j < 4; ++j) {
      const int gm = mBase + wm * 64 + mt * 16 + q4 * 4 + j;
      if (gm >= M) continue;
      if (EPI == 0) {
        const int b = gm / NTOK;
        const int t = gm - b * NTOK;
#pragma unroll
        for (int nt = 0; nt < 4; ++nt) {
          const int gc = nBase + wn * 64 + nt * 16 + l15;
          float v = acc[mt][nt][j] + bias[gc];
          const int three = gc / 768;
          const int hd = gc - three * 768;
          const int h = hd >> 6, d = hd & 63;
          const int bh = b * 12 + h;
          if (three == 2) {
            o_vt[((size_t)bh * 64 + d) * NKVPAD + t] = __float2bfloat16(v);
          } else {
            if (t > 0) {
              const float pv = acc[mt][nt ^ 2][j] + bias[gc ^ 32];
              const int so = (t - 1) * 64 + d;
              v = v * cosp[so] + ((d < 32) ? -pv : pv) * sinp[so];
            }
            const __hip_bfloat16 bv = __float2bfloat16(v);
            if (three == 0)
              o_q[((size_t)bh * NTOK + t) * 64 + d] = bv;
            else
              o_k[((size_t)bh * NTOK + t) * 64 + d] = bv;
          }
        }
      } else {
#pragma unroll
        for (int nt = 0; nt < 4; ++nt) {
          const int gc = nBase + wn * 64 + nt * 16 + l15;
          o_f32[(size_t)gm * 768 + gc] = acc[mt][nt][j] + bias[gc];
        }
      }
    }
}

// ===== K2: flash attention, 4 waves x 32 q-rows, KV tiles of 64 =====
__global__ __launch_bounds__(256) void k_attn(
    const __hip_bfloat16* __restrict__ Q, const __hip_bfloat16* __restrict__ Kk,
    const __hip_bfloat16* __restrict__ VT, __hip_bfloat16* __restrict__ ao) {
  __shared__ __hip_bfloat16 Pl[4][32][72]; // per-wave P tile, padded rows
  const int tid = threadIdx.x, w = tid >> 6, lane = tid & 63;
  const int l15 = lane & 15, q4 = lane >> 4;
  const int bh = blockIdx.y;
  const int qb = blockIdx.x * 128 + w * 32;
  const size_t qbase = (size_t)bh * NTOK * 64;

  // Q fragments (rows clamped; pad rows are discarded at store)
  bf16x8 qa[2][2];
#pragma unroll
  for (int mt = 0; mt < 2; ++mt) {
    int t = qb + mt * 16 + l15;
    if (t > NTOK - 1) t = NTOK - 1;
#pragma unroll
    for (int ks = 0; ks < 2; ++ks)
      qa[mt][ks] = *(const bf16x8*)(Q + qbase + (size_t)t * 64 + ks * 32 + q4 * 8);
  }

  f32x4 accO[2][4] = {};
  float mrun[2][4], lrun[2][4];
#pragma unroll
  for (int mt = 0; mt < 2; ++mt)
#pragma unroll
    for (int j = 0; j < 4; ++j) {
      mrun[mt][j] = -1e30f;
      lrun[mt][j] = 0.0f;
    }

  for (int kt = 0; kt < 17; ++kt) {
    const int kb0 = kt * 64;
    // S = Q K^T
    f32x4 s[2][4] = {};
    {
      bf16x8 kfr[2][4];
#pragma unroll
      for (int nt = 0; nt < 4; ++nt) {
        int krow = kb0 + nt * 16 + l15;
        if (krow > NTOK - 1) krow = NTOK - 1;
#pragma unroll
        for (int ks = 0; ks < 2; ++ks)
          kfr[ks][nt] =
              *(const bf16x8*)(Kk + qbase + (size_t)krow * 64 + ks * 32 + q4 * 8);
      }
#pragma unroll
      for (int mt = 0; mt < 2; ++mt)
#pragma unroll
        for (int nt = 0; nt < 4; ++nt)
#pragma unroll
          for (int ks = 0; ks < 2; ++ks)
            s[mt][nt] = mfma_bf16(qa[mt][ks], kfr[ks][nt], s[mt][nt]);
    }
    // online softmax (rows live in 16-lane groups; reduce via shfl_xor 1..8)
#pragma unroll
    for (int mt = 0; mt < 2; ++mt)
#pragma unroll
      for (int j = 0; j < 4; ++j) {
        float sv[4];
        float mx = -1e30f;
#pragma unroll
        for (int nt = 0; nt < 4; ++nt) {
          float v = s[mt][nt][j] * SCALE;
          if (kb0 + nt * 16 + l15 > NTOK - 1) v = -1e30f;
          sv[nt] = v;
          mx = fmaxf(mx, v);
        }
#pragma unroll
        for (int off = 1; off < 16; off <<= 1) mx = fmaxf(mx, __shfl_xor(mx, off));
        const float mold = mrun[mt][j];
        const float mnew = fmaxf(mold, mx);
        const float fsc = __expf(mold - mnew);
        float sum = 0.0f;
        __hip_bfloat16 pb[4];
#pragma unroll
        for (int nt = 0; nt < 4; ++nt) {
          float p = __expf(sv[nt] - mnew);
          sum += p;
          pb[nt] = __float2bfloat16(p);
        }
#pragma unroll
        for (int off = 1; off < 16; off <<= 1) sum += __shfl_xor(sum, off);
        mrun[mt][j] = mnew;
        lrun[mt][j] = lrun[mt][j] * fsc + sum;
#pragma unroll
        for (int nd = 0; nd < 4; ++nd) accO[mt][nd][j] *= fsc;
        const int row = mt * 16 + q4 * 4 + j;
#pragma unroll
        for (int nt = 0; nt < 4; ++nt) Pl[w][row][nt * 16 + l15] = pb[nt];
      }
    // PV (wave-private LDS; compiler orders ds_write->ds_read via lgkmcnt)
    bf16x8 pa[2][2], vf[2][4];
#pragma unroll
    for (int mt = 0; mt < 2; ++mt)
#pragma unroll
      for (int ks = 0; ks < 2; ++ks)
        pa[mt][ks] = *(const bf16x8*)&Pl[w][mt * 16 + l15][ks * 32 + q4 * 8];
#pragma unroll
    for (int nd = 0; nd < 4; ++nd)
#pragma unroll
      for (int ks = 0; ks < 2; ++ks)
        vf[ks][nd] = *(const bf16x8*)(VT + ((size_t)bh * 64 + nd * 16 + l15) * NKVPAD +
                                      kb0 + ks * 32 + q4 * 8);
#pragma unroll
    for (int mt = 0; mt < 2; ++mt)
#pragma unroll
      for (int nd = 0; nd < 4; ++nd)
#pragma unroll
        for (int ks = 0; ks < 2; ++ks)
          accO[mt][nd] = mfma_bf16(pa[mt][ks], vf[ks][nd], accO[mt][nd]);
  }

  // store attn_out bf16 at [b*1025+t][h*64+d]
  const int b = bh / 12, h = bh - (bh / 12) * 12;
#pragma unroll
  for (int mt = 0; mt < 2; ++mt)
#pragma unroll
    for (int j = 0; j < 4; ++j) {
      const int t = qb + mt * 16 + q4 * 4 + j;
      if (t > NTOK - 1) continue;
      const float inv = 1.0f / lrun[mt][j];
      const size_t ro = ((size_t)(b * NTOK + t)) * 768 + h * 64;
#pragma unroll
      for (int nd = 0; nd < 4; ++nd) {
        const int d = nd * 16 + l15;
        ao[ro + d] = __float2bfloat16(accO[mt][nd][j] * inv);
      }
    }
}

extern "C" void kernel_launch(void* const* d_in, const int* in_sizes, int n_in,
                              void* d_out, int out_size, void* d_ws, size_t ws_size,
                              hipStream_t stream) {
  const float* x = (const float*)d_in[0];
  const float* sinp = (const float*)d_in[1];
  const float* cosp = (const float*)d_in[2];
  const float* qkvw = (const float*)d_in[3];
  const float* qkvb = (const float*)d_in[4];
  const float* projw = (const float*)d_in[5];
  const float* projb = (const float*)d_in[6];

  char* ws = (char*)d_ws;
  __hip_bfloat16* xhi = (__hip_bfloat16*)(ws + OFF_XHI);
  __hip_bfloat16* xlo = (__hip_bfloat16*)(ws + OFF_XLO);
  __hip_bfloat16* wqhi = (__hip_bfloat16*)(ws + OFF_WQHI);
  __hip_bfloat16* pwhi = (__hip_bfloat16*)(ws + OFF_PWHI);
  __hip_bfloat16* pwlo = (__hip_bfloat16*)(ws + OFF_PWLO);
  __hip_bfloat16* qb = (__hip_bfloat16*)(ws + OFF_Q);
  __hip_bfloat16* kb = (__hip_bfloat16*)(ws + OFF_K);
  __hip_bfloat16* vt = (__hip_bfloat16*)(ws + OFF_VT);
  __hip_bfloat16* ao = (__hip_bfloat16*)(ws + OFF_AO);

  // K0: converts (x gets zero tail to MP rows; qkv_w hi only; proj_w hi+lo)
  {
    int n_src = M * KDIM, n_dst = MP * KDIM;
    k_split<<<(n_dst + 255) / 256, 256, 0, stream>>>(x, xhi, xlo, n_src, n_dst);
    int nw = NQKV * KDIM;
    k_tobf16<<<(nw + 255) / 256, 256, 0, stream>>>(qkvw, wqhi, nw);
    int np = KDIM * KDIM;
    k_split<<<(np + 255) / 256, 256, 0, stream>>>(projw, pwhi, pwlo, np, np);
    int nz = 96 * 64 * (NKVPAD - NTOK);
    k_zero_vt<<<(nz + 255) / 256, 256, 0, stream>>>(vt);
  }
  // K1: QKV GEMM (x split, w single) + bias + RoPE -> q, k, vT
  k_gemm<0, true><<<dim3(NQKV / 128, MP / 128), 256, 0, stream>>>(
      xhi, xlo, wqhi, qkvb, sinp, cosp, qb, kb, vt, nullptr);
  // K2: flash attention -> attn_out bf16
  k_attn<<<dim3(9, 96), 256, 0, stream>>>(qb, kb, vt, ao);
  // K3: proj GEMM (attn_out single, w split) + bias -> fp32 out
  k_gemm<1, false><<<dim3(KDIM / 128, MP / 128), 256, 0, stream>>>(
      ao, pwlo, pwhi, projb, nullptr, nullptr, nullptr, nullptr, nullptr,
      (float*)d_out);
}